// Round 1
// 1108.920 us; speedup vs baseline: 1.0117x; 1.0117x over previous
//
#include <hip/hip_runtime.h>
#include <math.h>

#define N_NODES 100000
#define N_EDGES 3200000
#define SCAN_NB ((N_NODES + 255) / 256)   // 391
#define PLANE 800000                      // floats per feature-half plane (N*8)
#define X_FLOATS (N_NODES * 131)          // 13,100,000

// Two-phase CSR build: 8 dst-range buckets (one per XCD via blockIdx%8 heuristic)
#define N_SHARDS 8
#define NODES_PER_SHARD (N_NODES / N_SHARDS)   // 12500
#define BKT_CHUNK 2000
#define BKT_NB (N_EDGES / BKT_CHUNK)           // 1600 blocks
#define BKT_LDS_CAP 448                        // per-bucket LDS staging (mean 250, +13 sigma)
#define BUCKET_CAP 425984                      // per-bucket global region (mean 400000, +43 sigma)
#define SC2_SEGS 800                           // segments per bucket in phase 2

// MLP pass A tiling: 128-node tile, k staged in 4 chunks of <=33
#define TILE_NODES 128
#define KCH 33
#define MLP1_NB ((N_NODES + TILE_NODES - 1) / TILE_NODES)   // 782

// ---------------- CSR build ----------------

__global__ void k_init(int* __restrict__ count, int* __restrict__ bcnt) {
    int i = blockIdx.x * blockDim.x + threadIdx.x;
    if (i < N_NODES) count[i] = 0;
    if (i < N_SHARDS) bcnt[i] = 0;
}

// Phase 1: single coalesced pass over edges. Fused degree histogram + bucket
// classification. pack = (dst_local << 17) | src  (dst_local < 12500 -> 14 bits,
// src < 100000 -> 17 bits, total 31 bits). LDS-staged, flushed with coalesced
// NT stores so bucket data never pollutes L2.
__global__ __launch_bounds__(256) void k_bucket(
        const int* __restrict__ src, const int* __restrict__ dst,
        int* __restrict__ count, int* __restrict__ bcnt,
        unsigned int* __restrict__ bdata) {
    __shared__ unsigned int buf[N_SHARDS * BKT_LDS_CAP];   // 14336 B
    __shared__ int lcnt[N_SHARDS];
    __shared__ int gbase[N_SHARDS];
    const int t = threadIdx.x;
    if (t < N_SHARDS) lcnt[t] = 0;
    __syncthreads();

    const int e0 = blockIdx.x * BKT_CHUNK;
    for (int e = e0 + t; e < e0 + BKT_CHUNK; e += 256) {
        int d = __builtin_nontemporal_load(&dst[e]);
        int s = __builtin_nontemporal_load(&src[e]);
        atomicAdd(&count[d], 1);                      // fused histogram
        int b = d / NODES_PER_SHARD;                  // magic-mul (const divisor)
        int dloc = d - b * NODES_PER_SHARD;
        unsigned int pack = ((unsigned int)dloc << 17) | (unsigned int)s;
        int p = atomicAdd(&lcnt[b], 1);               // LDS atomic
        buf[b * BKT_LDS_CAP + p] = pack;
    }
    __syncthreads();
    if (t < N_SHARDS) gbase[t] = atomicAdd(&bcnt[t], lcnt[t]);
    __syncthreads();
#pragma unroll
    for (int b = 0; b < N_SHARDS; ++b) {
        int n = lcnt[b];
        unsigned int* out = bdata + (size_t)b * BUCKET_CAP + gbase[b];
        for (int i = t; i < n; i += 256)
            __builtin_nontemporal_store(buf[b * BKT_LDS_CAP + i], &out[i]);
    }
}

__global__ __launch_bounds__(256) void k_scan1(const int* __restrict__ count,
                                               int* __restrict__ row_start,
                                               int* __restrict__ bsum) {
    __shared__ int tmp[256];
    const int t = threadIdx.x;
    const int i = blockIdx.x * 256 + t;
    int v = (i < N_NODES) ? count[i] : 0;
    tmp[t] = v;
    __syncthreads();
    for (int off = 1; off < 256; off <<= 1) {
        int a = (t >= off) ? tmp[t - off] : 0;
        __syncthreads();
        tmp[t] += a;
        __syncthreads();
    }
    if (i < N_NODES) row_start[i] = tmp[t] - v;   // exclusive
    if (t == 255) bsum[blockIdx.x] = tmp[255];
}

__global__ __launch_bounds__(512) void k_scan2(int* __restrict__ bsum) {
    __shared__ int tmp[512];
    const int t = threadIdx.x;
    int v = (t < SCAN_NB) ? bsum[t] : 0;
    tmp[t] = v;
    __syncthreads();
    for (int off = 1; off < 512; off <<= 1) {
        int a = (t >= off) ? tmp[t - off] : 0;
        __syncthreads();
        tmp[t] += a;
        __syncthreads();
    }
    if (t < SCAN_NB) bsum[t] = tmp[t] - v;   // exclusive
}

__global__ __launch_bounds__(256) void k_scan3(const int* __restrict__ count,
                                               int* __restrict__ row_start,
                                               const int* __restrict__ bsum,
                                               int* __restrict__ cursor,
                                               float* __restrict__ dinv) {
    const int i = blockIdx.x * 256 + threadIdx.x;
    if (i >= N_NODES) return;
    int rs = row_start[i] + bsum[blockIdx.x];
    row_start[i] = rs;
    cursor[i] = rs;
    dinv[i] = 1.0f / sqrtf((float)(count[i] + 1));   // deg includes self-loop
}

// Phase 2: drain one bucket per XCD (blockIdx&7). Working set per XCD =
// 1.6 MB csr slice + 50 KB cursor slice, L2-resident; the only streaming
// traffic is the NT bucket read -> dirty csr lines accumulate all 16 writes
// and evict once (kills the old 10x write amplification).
__global__ __launch_bounds__(256) void k_scatter2(
        const unsigned int* __restrict__ bdata,
        const int* __restrict__ bcnt,
        int* __restrict__ cursor,
        int* __restrict__ csr_src) {
    const int b = blockIdx.x & (N_SHARDS - 1);
    const int seg = blockIdx.x >> 3;
    const int total = bcnt[b];
    const int per = (total + SC2_SEGS - 1) / SC2_SEGS;
    const int i0 = seg * per;
    const int i1 = min(i0 + per, total);
    const unsigned int* data = bdata + (size_t)b * BUCKET_CAP;
    for (int i = i0 + threadIdx.x; i < i1; i += 256) {
        unsigned int pack = __builtin_nontemporal_load(&data[i]);
        int s = (int)(pack & 0x1FFFFu);
        int d = b * NODES_PER_SHARD + (int)(pack >> 17);
        int pos = atomicAdd(&cursor[d], 1);
        csr_src[pos] = s;
    }
}

// ---------------- MLP pass A: layer 1 (131 -> 64), k-chunked LDS staging ----------------
// 256 threads / 128-node tile: thread half (t>>7, forced wave-uniform) owns 32 of
// the 64 outputs -> 32 accumulators/thread, no spill. x staged per k-chunk
// (128x33 = 16.9 KB) -> 8+ blocks/CU co-resident. Stride-33 LDS reads: 2-way
// bank aliasing = free. Weights via SGPR (uniform address). Output
// feature-major h1T[j][node], coalesced.

__global__ __launch_bounds__(256) void k_mlp1(
        const float* __restrict__ x,
        const float* __restrict__ W1, const float* __restrict__ b1,
        float* __restrict__ h1T) {
    __shared__ float xs[TILE_NODES * KCH];   // 16896 B
    const int t = threadIdx.x;
    const int nl = t & 127;
    const int half_u = __builtin_amdgcn_readfirstlane(t >> 7);  // wave-uniform
    const int nbase = blockIdx.x * TILE_NODES;
    const int node = nbase + nl;

    float a[32];
#pragma unroll
    for (int j = 0; j < 32; ++j) a[j] = b1[half_u * 32 + j];

    for (int kc = 0; kc < 4; ++kc) {
        const int k0 = kc * KCH;
        const int len = (k0 + KCH <= 131) ? KCH : (131 - k0);   // 33,33,33,32
        __syncthreads();
        // stage chunk: xs[r*33 + c] = x[(nbase+r)*131 + k0 + c]
        for (int i = t; i < TILE_NODES * KCH; i += 256) {
            int r = i / KCH;
            int c = i - r * KCH;
            int gr = nbase + r;
            xs[i] = (c < len && gr < N_NODES) ? x[(long)gr * 131 + k0 + c] : 0.0f;
        }
        __syncthreads();
        const float* myrow = xs + nl * KCH;
        for (int kk = 0; kk < len; ++kk) {
            float xk = myrow[kk];
            const float* wr = W1 + (k0 + kk) * 64 + half_u * 32;   // uniform -> s_load
#pragma unroll
            for (int j = 0; j < 32; ++j) a[j] += xk * wr[j];
        }
    }

    if (node < N_NODES) {
#pragma unroll
        for (int j = 0; j < 32; ++j)
            h1T[(half_u * 32 + j) * N_NODES + node] = tanhf(a[j]);
    }
}

// ---------------- MLP pass B: 64 -> 32 -> 16 -> conv-fuse ----------------

__global__ __launch_bounds__(256) void k_mlp2(
        const float* __restrict__ h1T,
        const float* __restrict__ W2, const float* __restrict__ b2,
        const float* __restrict__ W3, const float* __restrict__ b3,
        const float* __restrict__ Wc1,
        const float* __restrict__ dinv,
        float* __restrict__ up) {
    const int node = blockIdx.x * 256 + threadIdx.x;
    if (node >= N_NODES) return;

    float a2[32];
#pragma unroll
    for (int j = 0; j < 32; ++j) a2[j] = b2[j];
    for (int k = 0; k < 64; ++k) {
        float hk = h1T[k * N_NODES + node];           // coalesced
        const float* wr = W2 + k * 32;                // uniform -> s_load
#pragma unroll
        for (int j = 0; j < 32; ++j) a2[j] += hk * wr[j];
    }
#pragma unroll
    for (int j = 0; j < 32; ++j) a2[j] = tanhf(a2[j]);

    float a3[16];
#pragma unroll
    for (int j = 0; j < 16; ++j) a3[j] = b3[j];
#pragma unroll 4
    for (int k = 0; k < 32; ++k) {
        float hk = a2[k];
        const float* wr = W3 + k * 16;
#pragma unroll
        for (int j = 0; j < 16; ++j) a3[j] += hk * wr[j];
    }

    float dv = dinv[node];
    float uo[16];
#pragma unroll
    for (int j = 0; j < 16; ++j) uo[j] = 0.0f;
#pragma unroll 4
    for (int k = 0; k < 16; ++k) {
        float hk = a3[k];
        const float* wr = Wc1 + k * 16;
#pragma unroll
        for (int j = 0; j < 16; ++j) uo[j] += hk * wr[j];
    }
    float4* p0 = reinterpret_cast<float4*>(up + (long)node * 8);
    float4* p1 = reinterpret_cast<float4*>(up + PLANE + (long)node * 8);
    float4 v;
    v.x = uo[0] * dv; v.y = uo[1] * dv; v.z = uo[2] * dv; v.w = uo[3] * dv; p0[0] = v;
    v.x = uo[4] * dv; v.y = uo[5] * dv; v.z = uo[6] * dv; v.w = uo[7] * dv; p0[1] = v;
    v.x = uo[8] * dv; v.y = uo[9] * dv; v.z = uo[10] * dv; v.w = uo[11] * dv; p1[0] = v;
    v.x = uo[12] * dv; v.y = uo[13] * dv; v.z = uo[14] * dv; v.w = uo[15] * dv; p1[1] = v;
}

// ---------------- Aggregation over one feature-half plane ----------------

__global__ __launch_bounds__(256) void k_aggh(
        const float* __restrict__ up,
        const int* __restrict__ row_start,
        const int* __restrict__ count,
        const int* __restrict__ csr_src,
        const float* __restrict__ dinv,
        const float* __restrict__ bias,
        float* __restrict__ hp) {
    const int shard = blockIdx.x & 7;
    const int half = shard & 1;
    const int quarter = shard >> 1;
    const int wave = threadIdx.x >> 6;
    const int lane = threadIdx.x & 63;
    const int f = lane & 7;
    const int grp = (lane >> 3) & 3;
    const int nsel = lane >> 5;
    const int node = quarter * 25000 + (blockIdx.x >> 3) * 8 + wave * 2 + nsel;

    const float* u = up + half * PLANE;
    const int rs = row_start[node];
    const int cnt = count[node];
    const float dv = dinv[node];

    int cmax = max(cnt, __shfl_xor(cnt, 32, 64));   // wave-uniform loop bound

    float acc = 0.0f;
    for (int base = 0; base < cmax; base += 32) {
        int idx = csr_src[rs + base + (lane & 31)];
#pragma unroll
        for (int k = 0; k < 8; ++k) {
            int e = base + 4 * k + grp;
            int s = __shfl(idx, (lane & 32) + 4 * k + grp, 64);
            if (e < cnt) acc += u[s * 8 + f];
        }
    }
    acc += __shfl_xor(acc, 8, 64);
    acc += __shfl_xor(acc, 16, 64);
    acc += u[node * 8 + f];                 // self-loop (u already dinv[src]-scaled)

    float hn = tanhf(dv * acc + bias[half * 8 + f]);
    if (grp == 0) hp[half * PLANE + node * 8 + f] = hn;
}

// ---------------- Per-node 16x16 transform (full feature rows) ----------------

__global__ __launch_bounds__(256) void k_trans(
        const float* __restrict__ hp,
        const float* __restrict__ dinv,
        const float* __restrict__ W,
        const float* __restrict__ bcls,
        float* __restrict__ up_next,
        float* __restrict__ out,
        int mode) {
    int node = blockIdx.x * 256 + threadIdx.x;
    if (node >= N_NODES) return;

    const float4* p0 = reinterpret_cast<const float4*>(hp + (long)node * 8);
    const float4* p1 = reinterpret_cast<const float4*>(hp + PLANE + (long)node * 8);
    float4 ha = p0[0], hb = p0[1], hc = p1[0], hd = p1[1];
    float h[16] = {ha.x, ha.y, ha.z, ha.w, hb.x, hb.y, hb.z, hb.w,
                   hc.x, hc.y, hc.z, hc.w, hd.x, hd.y, hd.z, hd.w};

    if (mode == 0) {
        float dv = dinv[node];
        float o[16];
#pragma unroll
        for (int j = 0; j < 16; ++j) o[j] = 0.0f;
#pragma unroll 4
        for (int k = 0; k < 16; ++k) {
            float hk = h[k];
#pragma unroll
            for (int j = 0; j < 16; ++j) o[j] += hk * W[k * 16 + j];
        }
        float4* q0 = reinterpret_cast<float4*>(up_next + (long)node * 8);
        float4* q1 = reinterpret_cast<float4*>(up_next + PLANE + (long)node * 8);
        float4 v;
        v.x = o[0] * dv; v.y = o[1] * dv; v.z = o[2] * dv; v.w = o[3] * dv; q0[0] = v;
        v.x = o[4] * dv; v.y = o[5] * dv; v.z = o[6] * dv; v.w = o[7] * dv; q0[1] = v;
        v.x = o[8] * dv; v.y = o[9] * dv; v.z = o[10] * dv; v.w = o[11] * dv; q1[0] = v;
        v.x = o[12] * dv; v.y = o[13] * dv; v.z = o[14] * dv; v.w = o[15] * dv; q1[1] = v;
    } else {
        float c0 = bcls[0], c1 = bcls[1];
#pragma unroll
        for (int k = 0; k < 16; ++k) {
            c0 += h[k] * W[k * 2 + 0];
            c1 += h[k] * W[k * 2 + 1];
        }
        out[(long)node * 2 + 0] = c0;
        out[(long)node * 2 + 1] = c1;
        float4* ho = reinterpret_cast<float4*>(out + 200000 + (long)node * 16);
        ho[0] = ha; ho[1] = hb; ho[2] = hc; ho[3] = hd;
    }
}

// ---------------- launch ----------------

extern "C" void kernel_launch(void* const* d_in, const int* in_sizes, int n_in,
                              void* d_out, int out_size, void* d_ws, size_t ws_size,
                              hipStream_t stream) {
    const float* x    = (const float*)d_in[0];
    const int*   ei   = (const int*)d_in[1];
    const float* W1   = (const float*)d_in[2];
    const float* b1   = (const float*)d_in[3];
    const float* W2   = (const float*)d_in[4];
    const float* b2   = (const float*)d_in[5];
    const float* W3   = (const float*)d_in[6];
    const float* b3   = (const float*)d_in[7];
    const float* Wc1  = (const float*)d_in[8];
    const float* bc1  = (const float*)d_in[9];
    const float* Wg   = (const float*)d_in[10];
    const float* bg   = (const float*)d_in[11];
    const float* Wcls = (const float*)d_in[12];
    const float* bcls = (const float*)d_in[13];
    float* out = (float*)d_out;

    const int* src = ei;
    const int* dst = ei + N_EDGES;

    int* count     = (int*)d_ws;
    int* cursor    = count + N_NODES;
    int* row_start = cursor + N_NODES;
    float* dinv    = (float*)(row_start + N_NODES);
    int* bcnt      = (int*)(dinv + N_NODES);        // 16 ints (8 used, aligned)
    int* csr_src   = bcnt + 16;
    float* u       = (float*)(csr_src + N_EDGES);   // 2 planes of N*8 floats
    float* hp      = u + 2 * PLANE;                 // 2 planes of N*8 floats
    float* h1T     = hp + 2 * PLANE;                // 64 * N floats (25.6 MB)
    int* bsum      = csr_src;                       // consumed by k_scan3 before k_scatter2 writes
    unsigned int* bdata = (unsigned int*)h1T;       // 13.6 MB, dead before k_mlp1 writes h1T

    k_init<<<(N_NODES + 255) / 256, 256, 0, stream>>>(count, bcnt);
    k_bucket<<<BKT_NB, 256, 0, stream>>>(src, dst, count, bcnt, bdata);
    k_scan1<<<SCAN_NB, 256, 0, stream>>>(count, row_start, bsum);
    k_scan2<<<1, 512, 0, stream>>>(bsum);
    k_scan3<<<SCAN_NB, 256, 0, stream>>>(count, row_start, bsum, cursor, dinv);
    k_scatter2<<<SC2_SEGS * N_SHARDS, 256, 0, stream>>>(bdata, bcnt, cursor, csr_src);
    k_mlp1<<<MLP1_NB, 256, 0, stream>>>(x, W1, b1, h1T);
    k_mlp2<<<SCAN_NB, 256, 0, stream>>>(h1T, W2, b2, W3, b3, Wc1, dinv, u);

    for (int j = 0; j < 10; ++j) {
        const float* bias = (j < 5) ? bc1 : (bg + (long)(j - 5) * 16);
        k_aggh<<<25000, 256, 0, stream>>>(u, row_start, count, csr_src, dinv, bias, hp);
        if (j < 9) {
            const float* Wn = (j < 4) ? Wc1 : (Wg + (long)(j - 4) * 256);
            k_trans<<<SCAN_NB, 256, 0, stream>>>(hp, dinv, Wn, nullptr, u, nullptr, 0);
        } else {
            k_trans<<<SCAN_NB, 256, 0, stream>>>(hp, dinv, Wcls, bcls, nullptr, out, 1);
        }
    }
}

// Round 3
// 1050.162 us; speedup vs baseline: 1.0684x; 1.0560x over previous
//
#include <hip/hip_runtime.h>
#include <math.h>

#define N_NODES 100000
#define N_EDGES 3200000
#define SCAN_NB ((N_NODES + 255) / 256)   // 391
#define PLANE 800000                      // floats per feature-half plane (N*8)

// Two-phase CSR build: 128 dst-range buckets, LDS-resident CSR assembly.
#define N_BKT 128
#define NPB 782                           // nodes per bucket (128*782 = 100096 >= N)
#define HALF_NPB 391
#define BKT_CHUNK 2000
#define BKT_NB (N_EDGES / BKT_CHUNK)      // 1600 blocks
#define BKT_LDS_CAP 64                    // per-bucket LDS staging (mean 15.6, P(ovfl)~1e-18)
#define BUCKET_CAP 26624                  // per-bucket global region (mean 25000, +10 sigma)
#define SLICE_CAP 14336                   // LDS csr slice (mean 12512, +16 sigma)

// MLP pass A tiling: 128-node tile, k staged in 4 chunks of <=33
#define TILE_NODES 128
#define KCH 33
#define MLP1_NB ((N_NODES + TILE_NODES - 1) / TILE_NODES)   // 782

// ---------------- CSR build ----------------

__global__ void k_init(int* __restrict__ count, int* __restrict__ bcnt) {
    int i = blockIdx.x * blockDim.x + threadIdx.x;
    if (i < N_NODES) count[i] = 0;
    if (i < N_BKT) bcnt[i] = 0;
}

// Phase 1: single coalesced pass over edges. Fused degree histogram + 128-way
// bucket classification. pack = (dst_local << 17) | src (dloc < 782 -> 10 bits,
// src < 100000 -> 17 bits). LDS-staged, flushed with coalesced NT stores.
__global__ __launch_bounds__(256) void k_bucket(
        const int* __restrict__ src, const int* __restrict__ dst,
        int* __restrict__ count, int* __restrict__ bcnt,
        unsigned int* __restrict__ bdata) {
    __shared__ unsigned int buf[N_BKT * BKT_LDS_CAP];   // 32768 B
    __shared__ int lcnt[N_BKT];
    __shared__ int gbase[N_BKT];
    const int t = threadIdx.x;
    if (t < N_BKT) lcnt[t] = 0;
    __syncthreads();

    const int e0 = blockIdx.x * BKT_CHUNK;
    for (int e = e0 + t; e < e0 + BKT_CHUNK; e += 256) {
        int d = __builtin_nontemporal_load(&dst[e]);
        int s = __builtin_nontemporal_load(&src[e]);
        atomicAdd(&count[d], 1);                      // fused histogram
        int b = d / NPB;                              // magic-mul (const divisor)
        int dloc = d - b * NPB;
        unsigned int pack = ((unsigned int)dloc << 17) | (unsigned int)s;
        int p = atomicAdd(&lcnt[b], 1);               // LDS atomic
        if (p < BKT_LDS_CAP)                          // defensive clamp (never expected)
            buf[b * BKT_LDS_CAP + p] = pack;
    }
    __syncthreads();
    if (t < N_BKT) {
        int n = min(lcnt[t], BKT_LDS_CAP);
        lcnt[t] = n;
        gbase[t] = atomicAdd(&bcnt[t], n);
    }
    __syncthreads();
    const int wv = t >> 6, ln = t & 63;
    for (int b = wv; b < N_BKT; b += 4) {
        int n = lcnt[b];
        unsigned int* outp = bdata + (size_t)b * BUCKET_CAP + gbase[b];
        for (int i = ln; i < n; i += 64)
            __builtin_nontemporal_store(buf[b * BKT_LDS_CAP + i], &outp[i]);
    }
}

__global__ __launch_bounds__(256) void k_scan1(const int* __restrict__ count,
                                               int* __restrict__ row_start,
                                               int* __restrict__ bsum) {
    __shared__ int tmp[256];
    const int t = threadIdx.x;
    const int i = blockIdx.x * 256 + t;
    int v = (i < N_NODES) ? count[i] : 0;
    tmp[t] = v;
    __syncthreads();
    for (int off = 1; off < 256; off <<= 1) {
        int a = (t >= off) ? tmp[t - off] : 0;
        __syncthreads();
        tmp[t] += a;
        __syncthreads();
    }
    if (i < N_NODES) row_start[i] = tmp[t] - v;   // exclusive
    if (t == 255) bsum[blockIdx.x] = tmp[255];
}

__global__ __launch_bounds__(512) void k_scan2(int* __restrict__ bsum) {
    __shared__ int tmp[512];
    const int t = threadIdx.x;
    int v = (t < SCAN_NB) ? bsum[t] : 0;
    tmp[t] = v;
    __syncthreads();
    for (int off = 1; off < 512; off <<= 1) {
        int a = (t >= off) ? tmp[t - off] : 0;
        __syncthreads();
        tmp[t] += a;
        __syncthreads();
    }
    if (t < SCAN_NB) bsum[t] = tmp[t] - v;   // exclusive
}

__global__ __launch_bounds__(256) void k_scan3(const int* __restrict__ count,
                                               int* __restrict__ row_start,
                                               const int* __restrict__ bsum,
                                               float* __restrict__ dinv) {
    const int i = blockIdx.x * 256 + threadIdx.x;
    if (i >= N_NODES) return;
    int rs = row_start[i] + bsum[blockIdx.x];
    row_start[i] = rs;
    dinv[i] = 1.0f / sqrtf((float)(count[i] + 1));   // deg includes self-loop
}

// Phase 2: LDS-resident CSR assembly. One block per half-bucket (391 nodes,
// ~12.5K edges). Cursors + csr slice live in LDS; scan the bucket's packed
// stream, LDS-atomic scatter, then write the finished slice with coalesced
// NT stores. Every csr line written exactly once by exactly one block ->
// no partial-line eviction amplification, no global cursor atomics.
__global__ __launch_bounds__(512) void k_csr(
        const unsigned int* __restrict__ bdata,
        const int* __restrict__ bcnt,
        const int* __restrict__ row_start,
        int* __restrict__ csr_src) {
    __shared__ int lcur[HALF_NPB];
    __shared__ int lcsr[SLICE_CAP];
    const int b = blockIdx.x >> 1;
    const int half = blockIdx.x & 1;
    const int node_lo = b * NPB + half * HALF_NPB;
    int node_hi = b * NPB + (half ? NPB : HALF_NPB);
    if (node_hi > N_NODES) node_hi = N_NODES;
    const int t = threadIdx.x;
    const int base = row_start[node_lo];
    const int end = (node_hi == N_NODES) ? N_EDGES : row_start[node_hi];
    const int nn = node_hi - node_lo;
    for (int i = t; i < nn; i += 512)
        lcur[i] = row_start[node_lo + i] - base;
    __syncthreads();
    const int total = bcnt[b];
    const unsigned int* data = bdata + (size_t)b * BUCKET_CAP;
    for (int i = t; i < total; i += 512) {
        unsigned int pack = __builtin_nontemporal_load(&data[i]);
        int n = b * NPB + (int)(pack >> 17);
        if (n >= node_lo && n < node_hi) {
            int p = atomicAdd(&lcur[n - node_lo], 1);
            if (p < SLICE_CAP)                        // defensive clamp (never expected)
                lcsr[p] = (int)(pack & 0x1FFFFu);
        }
    }
    __syncthreads();
    const int slice = end - base;
    for (int i = t; i < slice; i += 512)
        __builtin_nontemporal_store(lcsr[i], &csr_src[base + i]);
}

// ---------------- MLP pass A: layer 1 (131 -> 64), k-chunked LDS staging ----------------
// 256 threads / 128-node tile: thread half (t>>7, forced wave-uniform) owns 32 of
// the 64 outputs -> 32 accumulators/thread, no spill. x staged per k-chunk
// (128x33 = 16.9 KB) -> 8+ blocks/CU co-resident. Stride-33 LDS reads: 2-way
// bank aliasing = free. Weights via SGPR (uniform address). Output
// feature-major h1T[j][node], coalesced.

__global__ __launch_bounds__(256) void k_mlp1(
        const float* __restrict__ x,
        const float* __restrict__ W1, const float* __restrict__ b1,
        float* __restrict__ h1T) {
    __shared__ float xs[TILE_NODES * KCH];   // 16896 B
    const int t = threadIdx.x;
    const int nl = t & 127;
    const int half_u = __builtin_amdgcn_readfirstlane(t >> 7);  // wave-uniform
    const int nbase = blockIdx.x * TILE_NODES;
    const int node = nbase + nl;

    float a[32];
#pragma unroll
    for (int j = 0; j < 32; ++j) a[j] = b1[half_u * 32 + j];

    for (int kc = 0; kc < 4; ++kc) {
        const int k0 = kc * KCH;
        const int len = (k0 + KCH <= 131) ? KCH : (131 - k0);   // 33,33,33,32
        __syncthreads();
        // stage chunk: xs[r*33 + c] = x[(nbase+r)*131 + k0 + c]
        for (int i = t; i < TILE_NODES * KCH; i += 256) {
            int r = i / KCH;
            int c = i - r * KCH;
            int gr = nbase + r;
            xs[i] = (c < len && gr < N_NODES) ? x[(long)gr * 131 + k0 + c] : 0.0f;
        }
        __syncthreads();
        const float* myrow = xs + nl * KCH;
        for (int kk = 0; kk < len; ++kk) {
            float xk = myrow[kk];
            const float* wr = W1 + (k0 + kk) * 64 + half_u * 32;   // uniform -> s_load
#pragma unroll
            for (int j = 0; j < 32; ++j) a[j] += xk * wr[j];
        }
    }

    if (node < N_NODES) {
#pragma unroll
        for (int j = 0; j < 32; ++j)
            h1T[(half_u * 32 + j) * N_NODES + node] = tanhf(a[j]);
    }
}

// ---------------- MLP pass B: 64 -> 32 -> 16 -> conv-fuse ----------------

__global__ __launch_bounds__(256) void k_mlp2(
        const float* __restrict__ h1T,
        const float* __restrict__ W2, const float* __restrict__ b2,
        const float* __restrict__ W3, const float* __restrict__ b3,
        const float* __restrict__ Wc1,
        const float* __restrict__ dinv,
        float* __restrict__ up) {
    const int node = blockIdx.x * 256 + threadIdx.x;
    if (node >= N_NODES) return;

    float a2[32];
#pragma unroll
    for (int j = 0; j < 32; ++j) a2[j] = b2[j];
    for (int k = 0; k < 64; ++k) {
        float hk = h1T[k * N_NODES + node];           // coalesced
        const float* wr = W2 + k * 32;                // uniform -> s_load
#pragma unroll
        for (int j = 0; j < 32; ++j) a2[j] += hk * wr[j];
    }
#pragma unroll
    for (int j = 0; j < 32; ++j) a2[j] = tanhf(a2[j]);

    float a3[16];
#pragma unroll
    for (int j = 0; j < 16; ++j) a3[j] = b3[j];
#pragma unroll 4
    for (int k = 0; k < 32; ++k) {
        float hk = a2[k];
        const float* wr = W3 + k * 16;
#pragma unroll
        for (int j = 0; j < 16; ++j) a3[j] += hk * wr[j];
    }

    float dv = dinv[node];
    float uo[16];
#pragma unroll
    for (int j = 0; j < 16; ++j) uo[j] = 0.0f;
#pragma unroll 4
    for (int k = 0; k < 16; ++k) {
        float hk = a3[k];
        const float* wr = Wc1 + k * 16;
#pragma unroll
        for (int j = 0; j < 16; ++j) uo[j] += hk * wr[j];
    }
    float4* p0 = reinterpret_cast<float4*>(up + (long)node * 8);
    float4* p1 = reinterpret_cast<float4*>(up + PLANE + (long)node * 8);
    float4 v;
    v.x = uo[0] * dv; v.y = uo[1] * dv; v.z = uo[2] * dv; v.w = uo[3] * dv; p0[0] = v;
    v.x = uo[4] * dv; v.y = uo[5] * dv; v.z = uo[6] * dv; v.w = uo[7] * dv; p0[1] = v;
    v.x = uo[8] * dv; v.y = uo[9] * dv; v.z = uo[10] * dv; v.w = uo[11] * dv; p1[0] = v;
    v.x = uo[12] * dv; v.y = uo[13] * dv; v.z = uo[14] * dv; v.w = uo[15] * dv; p1[1] = v;
}

// ---------------- Aggregation over one feature-half plane ----------------

__global__ __launch_bounds__(256) void k_aggh(
        const float* __restrict__ up,
        const int* __restrict__ row_start,
        const int* __restrict__ count,
        const int* __restrict__ csr_src,
        const float* __restrict__ dinv,
        const float* __restrict__ bias,
        float* __restrict__ hp) {
    const int shard = blockIdx.x & 7;
    const int half = shard & 1;
    const int quarter = shard >> 1;
    const int wave = threadIdx.x >> 6;
    const int lane = threadIdx.x & 63;
    const int f = lane & 7;
    const int grp = (lane >> 3) & 3;
    const int nsel = lane >> 5;
    const int node = quarter * 25000 + (blockIdx.x >> 3) * 8 + wave * 2 + nsel;

    const float* u = up + half * PLANE;
    const int rs = row_start[node];
    const int cnt = count[node];
    const float dv = dinv[node];

    int cmax = max(cnt, __shfl_xor(cnt, 32, 64));   // wave-uniform loop bound

    float acc = 0.0f;
    for (int base = 0; base < cmax; base += 32) {
        int idx = csr_src[rs + base + (lane & 31)];
#pragma unroll
        for (int k = 0; k < 8; ++k) {
            int e = base + 4 * k + grp;
            int s = __shfl(idx, (lane & 32) + 4 * k + grp, 64);
            if (e < cnt) acc += u[s * 8 + f];
        }
    }
    acc += __shfl_xor(acc, 8, 64);
    acc += __shfl_xor(acc, 16, 64);
    acc += u[node * 8 + f];                 // self-loop (u already dinv[src]-scaled)

    float hn = tanhf(dv * acc + bias[half * 8 + f]);
    if (grp == 0) hp[half * PLANE + node * 8 + f] = hn;
}

// ---------------- Per-node 16x16 transform (full feature rows) ----------------

__global__ __launch_bounds__(256) void k_trans(
        const float* __restrict__ hp,
        const float* __restrict__ dinv,
        const float* __restrict__ W,
        const float* __restrict__ bcls,
        float* __restrict__ up_next,
        float* __restrict__ out,
        int mode) {
    int node = blockIdx.x * 256 + threadIdx.x;
    if (node >= N_NODES) return;

    const float4* p0 = reinterpret_cast<const float4*>(hp + (long)node * 8);
    const float4* p1 = reinterpret_cast<const float4*>(hp + PLANE + (long)node * 8);
    float4 ha = p0[0], hb = p0[1], hc = p1[0], hd = p1[1];
    float h[16] = {ha.x, ha.y, ha.z, ha.w, hb.x, hb.y, hb.z, hb.w,
                   hc.x, hc.y, hc.z, hc.w, hd.x, hd.y, hd.z, hd.w};

    if (mode == 0) {
        float dv = dinv[node];
        float o[16];
#pragma unroll
        for (int j = 0; j < 16; ++j) o[j] = 0.0f;
#pragma unroll 4
        for (int k = 0; k < 16; ++k) {
            float hk = h[k];
#pragma unroll
            for (int j = 0; j < 16; ++j) o[j] += hk * W[k * 16 + j];
        }
        float4* q0 = reinterpret_cast<float4*>(up_next + (long)node * 8);
        float4* q1 = reinterpret_cast<float4*>(up_next + PLANE + (long)node * 8);
        float4 v;
        v.x = o[0] * dv; v.y = o[1] * dv; v.z = o[2] * dv; v.w = o[3] * dv; q0[0] = v;
        v.x = o[4] * dv; v.y = o[5] * dv; v.z = o[6] * dv; v.w = o[7] * dv; q0[1] = v;
        v.x = o[8] * dv; v.y = o[9] * dv; v.z = o[10] * dv; v.w = o[11] * dv; q1[0] = v;
        v.x = o[12] * dv; v.y = o[13] * dv; v.z = o[14] * dv; v.w = o[15] * dv; q1[1] = v;
    } else {
        float c0 = bcls[0], c1 = bcls[1];
#pragma unroll
        for (int k = 0; k < 16; ++k) {
            c0 += h[k] * W[k * 2 + 0];
            c1 += h[k] * W[k * 2 + 1];
        }
        out[(long)node * 2 + 0] = c0;
        out[(long)node * 2 + 1] = c1;
        float4* ho = reinterpret_cast<float4*>(out + 200000 + (long)node * 16);
        ho[0] = ha; ho[1] = hb; ho[2] = hc; ho[3] = hd;
    }
}

// ---------------- launch ----------------

extern "C" void kernel_launch(void* const* d_in, const int* in_sizes, int n_in,
                              void* d_out, int out_size, void* d_ws, size_t ws_size,
                              hipStream_t stream) {
    const float* x    = (const float*)d_in[0];
    const int*   ei   = (const int*)d_in[1];
    const float* W1   = (const float*)d_in[2];
    const float* b1   = (const float*)d_in[3];
    const float* W2   = (const float*)d_in[4];
    const float* b2   = (const float*)d_in[5];
    const float* W3   = (const float*)d_in[6];
    const float* b3   = (const float*)d_in[7];
    const float* Wc1  = (const float*)d_in[8];
    const float* bc1  = (const float*)d_in[9];
    const float* Wg   = (const float*)d_in[10];
    const float* bg   = (const float*)d_in[11];
    const float* Wcls = (const float*)d_in[12];
    const float* bcls = (const float*)d_in[13];
    float* out = (float*)d_out;

    const int* src = ei;
    const int* dst = ei + N_EDGES;

    int* count     = (int*)d_ws;
    int* row_start = count + N_NODES;
    float* dinv    = (float*)(row_start + N_NODES);
    int* bcnt      = (int*)(dinv + N_NODES);        // 128 ints
    int* csr_src   = bcnt + N_BKT;
    float* u       = (float*)(csr_src + N_EDGES);   // 2 planes of N*8 floats
    float* hp      = u + 2 * PLANE;                 // 2 planes of N*8 floats
    float* h1T     = hp + 2 * PLANE;                // 64 * N floats (25.6 MB)
    int* bsum      = csr_src;                       // consumed by k_scan3 before k_csr writes
    unsigned int* bdata = (unsigned int*)h1T;       // 13.6 MB, dead before k_mlp1 writes h1T

    k_init<<<(N_NODES + 255) / 256, 256, 0, stream>>>(count, bcnt);
    k_bucket<<<BKT_NB, 256, 0, stream>>>(src, dst, count, bcnt, bdata);
    k_scan1<<<SCAN_NB, 256, 0, stream>>>(count, row_start, bsum);
    k_scan2<<<1, 512, 0, stream>>>(bsum);
    k_scan3<<<SCAN_NB, 256, 0, stream>>>(count, row_start, bsum, dinv);
    k_csr<<<2 * N_BKT, 512, 0, stream>>>(bdata, bcnt, row_start, csr_src);
    k_mlp1<<<MLP1_NB, 256, 0, stream>>>(x, W1, b1, h1T);
    k_mlp2<<<SCAN_NB, 256, 0, stream>>>(h1T, W2, b2, W3, b3, Wc1, dinv, u);

    for (int j = 0; j < 10; ++j) {
        const float* bias = (j < 5) ? bc1 : (bg + (long)(j - 5) * 16);
        k_aggh<<<25000, 256, 0, stream>>>(u, row_start, count, csr_src, dinv, bias, hp);
        if (j < 9) {
            const float* Wn = (j < 4) ? Wc1 : (Wg + (long)(j - 4) * 256);
            k_trans<<<SCAN_NB, 256, 0, stream>>>(hp, dinv, Wn, nullptr, u, nullptr, 0);
        } else {
            k_trans<<<SCAN_NB, 256, 0, stream>>>(hp, dinv, Wcls, bcls, nullptr, out, 1);
        }
    }
}

// Round 4
// 955.127 us; speedup vs baseline: 1.1747x; 1.0995x over previous
//
#include <hip/hip_runtime.h>
#include <math.h>

#define N_NODES 100000
#define N_EDGES 3200000
#define SCAN_NB ((N_NODES + 255) / 256)   // 391
#define PLANE 800000                      // floats per feature-half plane (N*8)

// Two-phase CSR build: 128 dst-range buckets, LDS-resident CSR assembly.
// Degree histogram is derived per-bucket in k_csr (no global atomics anywhere).
#define N_BKT 128
#define NPB 782                           // nodes per bucket (128*782 = 100096 >= N)
#define HALF_NPB 391
#define BKT_CHUNK 2000
#define BKT_NB (N_EDGES / BKT_CHUNK)      // 1600 blocks
#define BKT_LDS_CAP 64                    // per-bucket LDS staging (mean 15.6, P(ovfl)~1e-18)
#define BUCKET_CAP 26624                  // per-bucket global region (mean 25000, +10 sigma)
#define SLICE_CAP 14336                   // LDS csr slice (mean 12512, +16 sigma)

// MLP pass A tiling: 128-node tile, k staged in 4 chunks of <=33
#define TILE_NODES 128
#define KCH 33
#define MLP1_NB ((N_NODES + TILE_NODES - 1) / TILE_NODES)   // 782

// ---------------- CSR build ----------------

__global__ void k_init(int* __restrict__ bcnt) {
    int i = threadIdx.x;
    if (i < N_BKT) bcnt[i] = 0;
}

// Phase 1: single coalesced pass over edges, pure bucketing (NO count atomics —
// the old 3.2M memory-side atomic RMWs were ~105 MB of fabric write traffic).
// pack = (dst_local << 17) | src (dloc < 782 -> 10 bits, src < 100000 -> 17 bits).
// LDS-staged, flushed with coalesced NT stores.
__global__ __launch_bounds__(256) void k_bucket(
        const int* __restrict__ src, const int* __restrict__ dst,
        int* __restrict__ bcnt,
        unsigned int* __restrict__ bdata) {
    __shared__ unsigned int buf[N_BKT * BKT_LDS_CAP];   // 32768 B
    __shared__ int lcnt[N_BKT];
    __shared__ int gbase[N_BKT];
    const int t = threadIdx.x;
    if (t < N_BKT) lcnt[t] = 0;
    __syncthreads();

    const int e0 = blockIdx.x * BKT_CHUNK;
    for (int e = e0 + t; e < e0 + BKT_CHUNK; e += 256) {
        int d = __builtin_nontemporal_load(&dst[e]);
        int s = __builtin_nontemporal_load(&src[e]);
        int b = d / NPB;                              // magic-mul (const divisor)
        int dloc = d - b * NPB;
        unsigned int pack = ((unsigned int)dloc << 17) | (unsigned int)s;
        int p = atomicAdd(&lcnt[b], 1);               // LDS atomic
        if (p < BKT_LDS_CAP)                          // defensive clamp (never expected)
            buf[b * BKT_LDS_CAP + p] = pack;
    }
    __syncthreads();
    if (t < N_BKT) {
        int n = min(lcnt[t], BKT_LDS_CAP);
        lcnt[t] = n;
        gbase[t] = atomicAdd(&bcnt[t], n);
    }
    __syncthreads();
    const int wv = t >> 6, ln = t & 63;
    for (int b = wv; b < N_BKT; b += 4) {
        int n = lcnt[b];
        unsigned int* outp = bdata + (size_t)b * BUCKET_CAP + gbase[b];
        for (int i = ln; i < n; i += 64)
            __builtin_nontemporal_store(buf[b * BKT_LDS_CAP + i], &outp[i]);
    }
}

// Exclusive scan of the 128 bucket totals. Nodes are range-partitioned by
// bucket, so bb[b] = row_start of bucket b's first node. Replaces the old
// full-node k_scan1/2/3 chain.
__global__ __launch_bounds__(128) void k_bscan(const int* __restrict__ bcnt,
                                               int* __restrict__ bb) {
    __shared__ int s[128];
    const int t = threadIdx.x;
    int v = bcnt[t];
    s[t] = v;
    __syncthreads();
    for (int off = 1; off < 128; off <<= 1) {
        int a = (t >= off) ? s[t - off] : 0;
        __syncthreads();
        s[t] += a;
        __syncthreads();
    }
    bb[t] = s[t] - v;   // exclusive
    if (t == 127) bb[128] = s[127];
}

// Phase 2: LDS-resident CSR assembly + per-bucket degree derivation.
// One block per half-bucket. Pass 1 over the bucket stream builds a 782-entry
// LDS histogram (no-return LDS atomics); wave-0 exclusive scan; coalesced
// writes of count/row_start/dinv for this half; pass 2 scatters into the LDS
// csr slice; coalesced NT flush. Every csr line written exactly once.
__global__ __launch_bounds__(512) void k_csr(
        const unsigned int* __restrict__ bdata,
        const int* __restrict__ bcnt,
        const int* __restrict__ bb,
        int* __restrict__ count,
        int* __restrict__ row_start,
        float* __restrict__ dinv,
        int* __restrict__ csr_src) {
    __shared__ int lhist[NPB];
    __shared__ int lrs[NPB];
    __shared__ int lcsr[SLICE_CAP];     // total LDS 63600 B
    const int b = blockIdx.x >> 1;
    const int half = blockIdx.x & 1;
    const int t = threadIdx.x;
    const int total = bcnt[b];
    const int bb_b = bb[b];
    const unsigned int* data = bdata + (size_t)b * BUCKET_CAP;

    for (int i = t; i < NPB; i += 512) lhist[i] = 0;
    __syncthreads();
    for (int i = t; i < total; i += 512) {
        unsigned int pack = __builtin_nontemporal_load(&data[i]);
        atomicAdd(&lhist[pack >> 17], 1);             // no-return LDS atomic
    }
    __syncthreads();
    // exclusive scan lhist -> lrs (wave 0: 13 elems/lane + shfl_up wave scan)
    if (t < 64) {
        int loc[13];
        int s = 0;
#pragma unroll
        for (int k = 0; k < 13; ++k) {
            int idx = t * 13 + k;
            int v = (idx < NPB) ? lhist[idx] : 0;
            loc[k] = v; s += v;
        }
        int run = s;
#pragma unroll
        for (int off = 1; off < 64; off <<= 1) {
            int o = __shfl_up(run, off, 64);
            if (t >= off) run += o;
        }
        int excl = run - s;
#pragma unroll
        for (int k = 0; k < 13; ++k) {
            int idx = t * 13 + k;
            if (idx < NPB) lrs[idx] = excl;
            excl += loc[k];
        }
    }
    __syncthreads();
    // per-node outputs for this half (coalesced)
    const int node_lo = b * NPB + half * HALF_NPB;
    int node_hi = b * NPB + (half ? NPB : HALF_NPB);
    if (node_hi > N_NODES) node_hi = N_NODES;
    const int nn = node_hi - node_lo;
    for (int i = t; i < nn; i += 512) {
        int dloc = half * HALF_NPB + i;
        int c = lhist[dloc];
        count[node_lo + i] = c;
        row_start[node_lo + i] = bb_b + lrs[dloc];
        dinv[node_lo + i] = 1.0f / sqrtf((float)(c + 1));   // deg incl self-loop
    }
    const int slice_off = lrs[half * HALF_NPB];
    const int slice_len = half ? (total - slice_off) : lrs[HALF_NPB];
    __syncthreads();   // lhist reads done -> safe to reuse as cursors
    const int dlo = half * HALF_NPB;
    const int dhi = dlo + HALF_NPB;
    for (int i = t; i < HALF_NPB; i += 512)
        lhist[dlo + i] = lrs[dlo + i] - slice_off;    // slice-local cursors
    __syncthreads();
    for (int i = t; i < total; i += 512) {
        unsigned int pack = __builtin_nontemporal_load(&data[i]);
        int dloc = (int)(pack >> 17);
        if (dloc >= dlo && dloc < dhi) {
            int p = atomicAdd(&lhist[dloc], 1);
            if (p < SLICE_CAP)                        // defensive clamp (never expected)
                lcsr[p] = (int)(pack & 0x1FFFFu);
        }
    }
    __syncthreads();
    const int gb = bb_b + slice_off;
    for (int i = t; i < slice_len; i += 512)
        __builtin_nontemporal_store(lcsr[i], &csr_src[gb + i]);
}

// ---------------- MLP pass A: layer 1 (131 -> 64), k-chunked LDS staging ----------------
// 256 threads / 128-node tile: thread half (t>>7, forced wave-uniform) owns 32 of
// the 64 outputs -> 32 accumulators/thread, no spill. x staged per k-chunk
// (128x33 = 16.9 KB) -> 8+ blocks/CU co-resident. Stride-33 LDS reads: 2-way
// bank aliasing = free. Weights via SGPR (uniform address). Output
// feature-major h1T[j][node], coalesced.

__global__ __launch_bounds__(256) void k_mlp1(
        const float* __restrict__ x,
        const float* __restrict__ W1, const float* __restrict__ b1,
        float* __restrict__ h1T) {
    __shared__ float xs[TILE_NODES * KCH];   // 16896 B
    const int t = threadIdx.x;
    const int nl = t & 127;
    const int half_u = __builtin_amdgcn_readfirstlane(t >> 7);  // wave-uniform
    const int nbase = blockIdx.x * TILE_NODES;
    const int node = nbase + nl;

    float a[32];
#pragma unroll
    for (int j = 0; j < 32; ++j) a[j] = b1[half_u * 32 + j];

    for (int kc = 0; kc < 4; ++kc) {
        const int k0 = kc * KCH;
        const int len = (k0 + KCH <= 131) ? KCH : (131 - k0);   // 33,33,33,32
        __syncthreads();
        // stage chunk: xs[r*33 + c] = x[(nbase+r)*131 + k0 + c]
        for (int i = t; i < TILE_NODES * KCH; i += 256) {
            int r = i / KCH;
            int c = i - r * KCH;
            int gr = nbase + r;
            xs[i] = (c < len && gr < N_NODES) ? x[(long)gr * 131 + k0 + c] : 0.0f;
        }
        __syncthreads();
        const float* myrow = xs + nl * KCH;
        for (int kk = 0; kk < len; ++kk) {
            float xk = myrow[kk];
            const float* wr = W1 + (k0 + kk) * 64 + half_u * 32;   // uniform -> s_load
#pragma unroll
            for (int j = 0; j < 32; ++j) a[j] += xk * wr[j];
        }
    }

    if (node < N_NODES) {
#pragma unroll
        for (int j = 0; j < 32; ++j)
            h1T[(half_u * 32 + j) * N_NODES + node] = tanhf(a[j]);
    }
}

// ---------------- MLP pass B: 64 -> 32 -> 16 -> conv-fuse ----------------

__global__ __launch_bounds__(256) void k_mlp2(
        const float* __restrict__ h1T,
        const float* __restrict__ W2, const float* __restrict__ b2,
        const float* __restrict__ W3, const float* __restrict__ b3,
        const float* __restrict__ Wc1,
        const float* __restrict__ dinv,
        float* __restrict__ up) {
    const int node = blockIdx.x * 256 + threadIdx.x;
    if (node >= N_NODES) return;

    float a2[32];
#pragma unroll
    for (int j = 0; j < 32; ++j) a2[j] = b2[j];
    for (int k = 0; k < 64; ++k) {
        float hk = h1T[k * N_NODES + node];           // coalesced
        const float* wr = W2 + k * 32;                // uniform -> s_load
#pragma unroll
        for (int j = 0; j < 32; ++j) a2[j] += hk * wr[j];
    }
#pragma unroll
    for (int j = 0; j < 32; ++j) a2[j] = tanhf(a2[j]);

    float a3[16];
#pragma unroll
    for (int j = 0; j < 16; ++j) a3[j] = b3[j];
#pragma unroll 4
    for (int k = 0; k < 32; ++k) {
        float hk = a2[k];
        const float* wr = W3 + k * 16;
#pragma unroll
        for (int j = 0; j < 16; ++j) a3[j] += hk * wr[j];
    }

    float dv = dinv[node];
    float uo[16];
#pragma unroll
    for (int j = 0; j < 16; ++j) uo[j] = 0.0f;
#pragma unroll 4
    for (int k = 0; k < 16; ++k) {
        float hk = a3[k];
        const float* wr = Wc1 + k * 16;
#pragma unroll
        for (int j = 0; j < 16; ++j) uo[j] += hk * wr[j];
    }
    float4* p0 = reinterpret_cast<float4*>(up + (long)node * 8);
    float4* p1 = reinterpret_cast<float4*>(up + PLANE + (long)node * 8);
    float4 v;
    v.x = uo[0] * dv; v.y = uo[1] * dv; v.z = uo[2] * dv; v.w = uo[3] * dv; p0[0] = v;
    v.x = uo[4] * dv; v.y = uo[5] * dv; v.z = uo[6] * dv; v.w = uo[7] * dv; p0[1] = v;
    v.x = uo[8] * dv; v.y = uo[9] * dv; v.z = uo[10] * dv; v.w = uo[11] * dv; p1[0] = v;
    v.x = uo[12] * dv; v.y = uo[13] * dv; v.z = uo[14] * dv; v.w = uo[15] * dv; p1[1] = v;
}

// ---------------- Aggregation over one feature-half plane ----------------

__global__ __launch_bounds__(256) void k_aggh(
        const float* __restrict__ up,
        const int* __restrict__ row_start,
        const int* __restrict__ count,
        const int* __restrict__ csr_src,
        const float* __restrict__ dinv,
        const float* __restrict__ bias,
        float* __restrict__ hp) {
    const int shard = blockIdx.x & 7;
    const int half = shard & 1;
    const int quarter = shard >> 1;
    const int wave = threadIdx.x >> 6;
    const int lane = threadIdx.x & 63;
    const int f = lane & 7;
    const int grp = (lane >> 3) & 3;
    const int nsel = lane >> 5;
    const int node = quarter * 25000 + (blockIdx.x >> 3) * 8 + wave * 2 + nsel;

    const float* u = up + half * PLANE;
    const int rs = row_start[node];
    const int cnt = count[node];
    const float dv = dinv[node];

    int cmax = max(cnt, __shfl_xor(cnt, 32, 64));   // wave-uniform loop bound

    float acc = 0.0f;
    for (int base = 0; base < cmax; base += 32) {
        int idx = csr_src[rs + base + (lane & 31)];
#pragma unroll
        for (int k = 0; k < 8; ++k) {
            int e = base + 4 * k + grp;
            int s = __shfl(idx, (lane & 32) + 4 * k + grp, 64);
            if (e < cnt) acc += u[s * 8 + f];
        }
    }
    acc += __shfl_xor(acc, 8, 64);
    acc += __shfl_xor(acc, 16, 64);
    acc += u[node * 8 + f];                 // self-loop (u already dinv[src]-scaled)

    float hn = tanhf(dv * acc + bias[half * 8 + f]);
    if (grp == 0) hp[half * PLANE + node * 8 + f] = hn;
}

// ---------------- Per-node 16x16 transform (full feature rows) ----------------

__global__ __launch_bounds__(256) void k_trans(
        const float* __restrict__ hp,
        const float* __restrict__ dinv,
        const float* __restrict__ W,
        const float* __restrict__ bcls,
        float* __restrict__ up_next,
        float* __restrict__ out,
        int mode) {
    int node = blockIdx.x * 256 + threadIdx.x;
    if (node >= N_NODES) return;

    const float4* p0 = reinterpret_cast<const float4*>(hp + (long)node * 8);
    const float4* p1 = reinterpret_cast<const float4*>(hp + PLANE + (long)node * 8);
    float4 ha = p0[0], hb = p0[1], hc = p1[0], hd = p1[1];
    float h[16] = {ha.x, ha.y, ha.z, ha.w, hb.x, hb.y, hb.z, hb.w,
                   hc.x, hc.y, hc.z, hc.w, hd.x, hd.y, hd.z, hd.w};

    if (mode == 0) {
        float dv = dinv[node];
        float o[16];
#pragma unroll
        for (int j = 0; j < 16; ++j) o[j] = 0.0f;
#pragma unroll 4
        for (int k = 0; k < 16; ++k) {
            float hk = h[k];
#pragma unroll
            for (int j = 0; j < 16; ++j) o[j] += hk * W[k * 16 + j];
        }
        float4* q0 = reinterpret_cast<float4*>(up_next + (long)node * 8);
        float4* q1 = reinterpret_cast<float4*>(up_next + PLANE + (long)node * 8);
        float4 v;
        v.x = o[0] * dv; v.y = o[1] * dv; v.z = o[2] * dv; v.w = o[3] * dv; q0[0] = v;
        v.x = o[4] * dv; v.y = o[5] * dv; v.z = o[6] * dv; v.w = o[7] * dv; q0[1] = v;
        v.x = o[8] * dv; v.y = o[9] * dv; v.z = o[10] * dv; v.w = o[11] * dv; q1[0] = v;
        v.x = o[12] * dv; v.y = o[13] * dv; v.z = o[14] * dv; v.w = o[15] * dv; q1[1] = v;
    } else {
        float c0 = bcls[0], c1 = bcls[1];
#pragma unroll
        for (int k = 0; k < 16; ++k) {
            c0 += h[k] * W[k * 2 + 0];
            c1 += h[k] * W[k * 2 + 1];
        }
        out[(long)node * 2 + 0] = c0;
        out[(long)node * 2 + 1] = c1;
        float4* ho = reinterpret_cast<float4*>(out + 200000 + (long)node * 16);
        ho[0] = ha; ho[1] = hb; ho[2] = hc; ho[3] = hd;
    }
}

// ---------------- launch ----------------

extern "C" void kernel_launch(void* const* d_in, const int* in_sizes, int n_in,
                              void* d_out, int out_size, void* d_ws, size_t ws_size,
                              hipStream_t stream) {
    const float* x    = (const float*)d_in[0];
    const int*   ei   = (const int*)d_in[1];
    const float* W1   = (const float*)d_in[2];
    const float* b1   = (const float*)d_in[3];
    const float* W2   = (const float*)d_in[4];
    const float* b2   = (const float*)d_in[5];
    const float* W3   = (const float*)d_in[6];
    const float* b3   = (const float*)d_in[7];
    const float* Wc1  = (const float*)d_in[8];
    const float* bc1  = (const float*)d_in[9];
    const float* Wg   = (const float*)d_in[10];
    const float* bg   = (const float*)d_in[11];
    const float* Wcls = (const float*)d_in[12];
    const float* bcls = (const float*)d_in[13];
    float* out = (float*)d_out;

    const int* src = ei;
    const int* dst = ei + N_EDGES;

    int* count     = (int*)d_ws;
    int* row_start = count + N_NODES;
    float* dinv    = (float*)(row_start + N_NODES);
    int* bcnt      = (int*)(dinv + N_NODES);        // 128 ints
    int* bb        = bcnt + N_BKT;                  // 129 ints (padded to 132)
    int* csr_src   = bb + 132;
    float* u       = (float*)(csr_src + N_EDGES);   // 2 planes of N*8 floats (16B-aligned)
    float* hp      = u + 2 * PLANE;                 // 2 planes of N*8 floats
    float* h1T     = hp + 2 * PLANE;                // 64 * N floats (25.6 MB)
    unsigned int* bdata = (unsigned int*)h1T;       // 13.6 MB, dead before k_mlp1 writes h1T

    k_init<<<1, 128, 0, stream>>>(bcnt);
    k_bucket<<<BKT_NB, 256, 0, stream>>>(src, dst, bcnt, bdata);
    k_bscan<<<1, 128, 0, stream>>>(bcnt, bb);
    k_csr<<<2 * N_BKT, 512, 0, stream>>>(bdata, bcnt, bb, count, row_start, dinv, csr_src);
    k_mlp1<<<MLP1_NB, 256, 0, stream>>>(x, W1, b1, h1T);
    k_mlp2<<<SCAN_NB, 256, 0, stream>>>(h1T, W2, b2, W3, b3, Wc1, dinv, u);

    for (int j = 0; j < 10; ++j) {
        const float* bias = (j < 5) ? bc1 : (bg + (long)(j - 5) * 16);
        k_aggh<<<25000, 256, 0, stream>>>(u, row_start, count, csr_src, dinv, bias, hp);
        if (j < 9) {
            const float* Wn = (j < 4) ? Wc1 : (Wg + (long)(j - 4) * 256);
            k_trans<<<SCAN_NB, 256, 0, stream>>>(hp, dinv, Wn, nullptr, u, nullptr, 0);
        } else {
            k_trans<<<SCAN_NB, 256, 0, stream>>>(hp, dinv, Wcls, bcls, nullptr, out, 1);
        }
    }
}